// Round 1
// baseline (2622.390 us; speedup 1.0000x reference)
//
#include <hip/hip_runtime.h>

#define A_CNT   5
#define NB      1024
#define DIM     512
#define NMEM    16384
#define TOPK    50
#define NSTEPS  5
#define H1N     256
#define H2N     128

#define TM      128
#define TN      128
#define KC      32
#define CAND_CAP 1024

struct TileDesc { int a; int s0; int nvalid; int pad; };

// ---------------------------------------------------------------------------
// 1 / (||keys_row|| + eps) for all A*N rows. One wave per row, 4 rows/block.
__global__ __launch_bounds__(256) void k_inv_norm(const float* __restrict__ keys,
                                                  float* __restrict__ inv) {
    int row  = blockIdx.x * 4 + (threadIdx.x >> 6);
    int lane = threadIdx.x & 63;
    const float* p = keys + (size_t)row * DIM;
    float ss = 0.f;
    for (int i = lane; i < DIM; i += 64) { float v = p[i]; ss += v * v; }
    for (int o = 32; o; o >>= 1) ss += __shfl_down(ss, o);
    ss = __shfl(ss, 0);
    if (lane == 0) inv[row] = 1.0f / (sqrtf(ss) + 1e-8f);
}

// ---------------------------------------------------------------------------
// qn[b] = x[b] / (||x[b]|| + eps). One block (256 thr) per row.
__global__ __launch_bounds__(256) void k_qnorm(const float* __restrict__ x,
                                               float* __restrict__ qn) {
    int row = blockIdx.x, tid = threadIdx.x;
    const float* p = x + (size_t)row * DIM;
    float ss = 0.f;
    for (int i = tid; i < DIM; i += 256) { float v = p[i]; ss += v * v; }
    for (int o = 32; o; o >>= 1) ss += __shfl_down(ss, o);
    __shared__ float w4[4];
    if ((tid & 63) == 0) w4[tid >> 6] = ss;
    __syncthreads();
    float tot = w4[0] + w4[1] + w4[2] + w4[3];
    float s = 1.0f / (sqrtf(tot) + 1e-8f);
    float* q = qn + (size_t)row * DIM;
    for (int i = tid; i < DIM; i += 256) q[i] = p[i] * s;
}

// ---------------------------------------------------------------------------
// Stable counting sort of batch rows by actions[:,t] (1 wave), plus tile
// descriptors (tiles of TM sorted rows, uniform action, not crossing chunk
// boundaries of cb rows).
__global__ void k_group(const int* __restrict__ actions, int t,
                        int* __restrict__ sorted_b, int* __restrict__ sorted_a,
                        TileDesc* __restrict__ descs, int cb, int maxd, int nch) {
    int lane = threadIdx.x;  // blockDim = 64
    for (int i = lane; i < nch * maxd; i += 64) descs[i].a = -1;
    __shared__ int gs[A_CNT + 1];
    int out_pos = 0;
    for (int a = 0; a < A_CNT; a++) {
        if (lane == 0) gs[a] = out_pos;
        for (int c = 0; c < NB; c += 64) {
            int b = c + lane;
            int act = actions[b * NSTEPS + t];
            unsigned long long m = __ballot(act == a);
            int rank = __popcll(m & ((1ULL << lane) - 1ULL));
            if (act == a) { sorted_b[out_pos + rank] = b; sorted_a[out_pos + rank] = a; }
            out_pos += __popcll(m);
        }
    }
    if (lane == 0) {
        gs[A_CNT] = NB;
        int ndc[4] = {0, 0, 0, 0};
        for (int a = 0; a < A_CNT; a++) {
            int s = gs[a], e = gs[a + 1];
            while (s < e) {
                int c = s / cb;
                int lim = min(e, (c + 1) * cb);
                int len = min(TM, lim - s);
                TileDesc d; d.a = a; d.s0 = s; d.nvalid = len; d.pad = 0;
                descs[c * maxd + ndc[c]++] = d;
                s += len;
            }
        }
    }
}

// ---------------------------------------------------------------------------
// sims[s][n] = dot(qn[sorted_b[s]], keys[a][n]) * inv_kn[a][n]
// f32 GEMM, 128x128 tile, 8x8 per-thread microtile, KC=32 LDS staging.
__global__ __launch_bounds__(256) void k_gemm(
    const float* __restrict__ qn, const float* __restrict__ keys,
    const float* __restrict__ inv_kn, const int* __restrict__ sorted_b,
    const TileDesc* __restrict__ descs, int chunk_row0,
    float* __restrict__ sims) {
    TileDesc d = descs[blockIdx.y];
    if (d.a < 0) return;
    int tid = threadIdx.x;
    int n0 = blockIdx.x * TN;
    __shared__ __align__(16) float As[KC][TM + 4];
    __shared__ __align__(16) float Bs[KC][TN + 4];
    __shared__ int rows[TM];
    if (tid < TM) {
        int s = d.s0 + min(tid, d.nvalid - 1);
        rows[tid] = sorted_b[s];
    }
    __syncthreads();
    float acc[8][8];
#pragma unroll
    for (int i = 0; i < 8; i++)
#pragma unroll
        for (int j = 0; j < 8; j++) acc[i][j] = 0.f;
    int ty = tid >> 4, tx = tid & 15;
    const float* kbase = keys + (size_t)d.a * NMEM * DIM;
    for (int k0 = 0; k0 < DIM; k0 += KC) {
#pragma unroll
        for (int i = 0; i < 4; i++) {       // A tile: 128 rows x 32 k
            int f4 = tid + i * 256;
            int r = f4 >> 3;
            int kq = (f4 & 7) * 4;
            float4 v = *(const float4*)(qn + (size_t)rows[r] * DIM + k0 + kq);
            As[kq + 0][r] = v.x; As[kq + 1][r] = v.y;
            As[kq + 2][r] = v.z; As[kq + 3][r] = v.w;
        }
#pragma unroll
        for (int i = 0; i < 4; i++) {       // B tile: 128 cols x 32 k
            int f4 = tid + i * 256;
            int n = f4 >> 3;
            int kq = (f4 & 7) * 4;
            float4 v = *(const float4*)(kbase + (size_t)(n0 + n) * DIM + k0 + kq);
            Bs[kq + 0][n] = v.x; Bs[kq + 1][n] = v.y;
            Bs[kq + 2][n] = v.z; Bs[kq + 3][n] = v.w;
        }
        __syncthreads();
#pragma unroll
        for (int k = 0; k < KC; k++) {
            float4 a0 = *(const float4*)&As[k][ty * 4];
            float4 a1 = *(const float4*)&As[k][64 + ty * 4];
            float4 b0 = *(const float4*)&Bs[k][tx * 4];
            float4 b1 = *(const float4*)&Bs[k][64 + tx * 4];
            float ar[8] = {a0.x, a0.y, a0.z, a0.w, a1.x, a1.y, a1.z, a1.w};
            float br[8] = {b0.x, b0.y, b0.z, b0.w, b1.x, b1.y, b1.z, b1.w};
#pragma unroll
            for (int i = 0; i < 8; i++)
#pragma unroll
                for (int j = 0; j < 8; j++) acc[i][j] += ar[i] * br[j];
        }
        __syncthreads();
    }
    // epilogue: scale by inv key norm, store
    const float* invp = inv_kn + (size_t)d.a * NMEM + n0;
    float invc[8];
#pragma unroll
    for (int j = 0; j < 4; j++) { invc[j] = invp[tx * 4 + j]; invc[4 + j] = invp[64 + tx * 4 + j]; }
    int sbase = d.s0 - chunk_row0;
#pragma unroll
    for (int i = 0; i < 8; i++) {
        int r = (i < 4) ? (ty * 4 + i) : (64 + ty * 4 + (i - 4));
        if (r < d.nvalid) {
            float* o = sims + (size_t)(sbase + r) * NMEM + n0;
            float4 s0, s1;
            s0.x = acc[i][0] * invc[0]; s0.y = acc[i][1] * invc[1];
            s0.z = acc[i][2] * invc[2]; s0.w = acc[i][3] * invc[3];
            s1.x = acc[i][4] * invc[4]; s1.y = acc[i][5] * invc[5];
            s1.z = acc[i][6] * invc[6]; s1.w = acc[i][7] * invc[7];
            *(float4*)(o + tx * 4) = s0;
            *(float4*)(o + 64 + tx * 4) = s1;
        }
    }
}

// ---------------------------------------------------------------------------
__device__ __forceinline__ unsigned fmap(float f) {
    unsigned u = __float_as_uint(f);
    return (u & 0x80000000u) ? ~u : (u | 0x80000000u);
}

// Exact top-50 (radix select over ordered-uint map, ties -> lowest index),
// softmax, weighted gather of mem_values -> cur_next[b]. One block per row.
__global__ __launch_bounds__(256) void k_topk(
    const float* __restrict__ sims, const int* __restrict__ sorted_b,
    const int* __restrict__ sorted_a, int chunk_row0,
    const float* __restrict__ memv, float* __restrict__ cur_next) {
    int tid = threadIdx.x;
    int s = chunk_row0 + blockIdx.x;
    int b = sorted_b[s], a = sorted_a[s];
    const float* row = sims + (size_t)blockIdx.x * NMEM;

    __shared__ unsigned hist[256];
    __shared__ unsigned sh_prefix;
    __shared__ int sh_need;
    __shared__ unsigned cnum;
    __shared__ unsigned short cidx[CAND_CAP];
    __shared__ unsigned cval[CAND_CAP];

    // pass 0: histogram of top byte (full row scan)
    hist[tid] = 0;
    if (tid == 0) { sh_prefix = 0; sh_need = TOPK; cnum = 0; }
    __syncthreads();
    for (int i = tid; i < NMEM; i += 256)
        atomicAdd(&hist[fmap(row[i]) >> 24], 1u);
    __syncthreads();
    if (tid == 0) {
        int need = TOPK, bsel = 0;
        for (int bb = 255; bb >= 0; bb--) {
            int c = (int)hist[bb];
            if (c >= need) { bsel = bb; break; }
            need -= c;
        }
        sh_need = need;
        sh_prefix = (unsigned)bsel << 24;
    }
    __syncthreads();
    unsigned b0 = sh_prefix >> 24;
    // candidate build: everything with top byte >= b0
    for (int i = tid; i < NMEM; i += 256) {
        unsigned u = fmap(row[i]);
        if ((u >> 24) >= b0) {
            unsigned p = atomicAdd(&cnum, 1u);
            if (p < CAND_CAP) { cidx[p] = (unsigned short)i; cval[p] = u; }
        }
    }
    __syncthreads();
    bool ovf = (cnum > CAND_CAP);
    int ncand = ovf ? 0 : (int)cnum;
    // passes 1..3
    for (int p = 1; p < 4; p++) {
        int shift = 24 - p * 8;
        hist[tid] = 0;
        __syncthreads();
        unsigned prefix = sh_prefix;
        unsigned himask = 0xFFFFFFFFu << (shift + 8);
        if (!ovf) {
            for (int i = tid; i < ncand; i += 256) {
                unsigned u = cval[i];
                if ((u & himask) == (prefix & himask))
                    atomicAdd(&hist[(u >> shift) & 255], 1u);
            }
        } else {
            for (int i = tid; i < NMEM; i += 256) {
                unsigned u = fmap(row[i]);
                if ((u & himask) == (prefix & himask))
                    atomicAdd(&hist[(u >> shift) & 255], 1u);
            }
        }
        __syncthreads();
        if (tid == 0) {
            int need = sh_need, bsel = 0;
            for (int bb = 255; bb >= 0; bb--) {
                int c = (int)hist[bb];
                if (c >= need) { bsel = bb; break; }
                need -= c;
            }
            sh_need = need;
            sh_prefix = prefix | ((unsigned)bsel << shift);
        }
        __syncthreads();
    }
    unsigned tau = sh_prefix;
    int rneed = sh_need;

    __shared__ int idxk[TOPK];
    __shared__ float wk[TOPK];
    __shared__ unsigned cnt_gt, cnt_eq;
    __shared__ int ties[128];
    if (tid < TOPK) idxk[tid] = 0;
    if (tid == 0) { cnt_gt = 0; cnt_eq = 0; }
    __syncthreads();
    if (!ovf) {
        for (int i = tid; i < ncand; i += 256) {
            unsigned u = cval[i];
            if (u > tau) { unsigned p = atomicAdd(&cnt_gt, 1u); if (p < TOPK) idxk[p] = cidx[i]; }
            else if (u == tau) { unsigned p = atomicAdd(&cnt_eq, 1u); if (p < 128) ties[p] = cidx[i]; }
        }
    } else {
        for (int i = tid; i < NMEM; i += 256) {
            unsigned u = fmap(row[i]);
            if (u > tau) { unsigned p = atomicAdd(&cnt_gt, 1u); if (p < TOPK) idxk[p] = i; }
            else if (u == tau) { unsigned p = atomicAdd(&cnt_eq, 1u); if (p < 128) ties[p] = i; }
        }
    }
    __syncthreads();
    if (tid == 0) {
        int ng = (int)cnt_gt; if (ng > TOPK) ng = TOPK;
        int ne = (int)cnt_eq; if (ne > 128) ne = 128;
        for (int j = 0; j < rneed && j < ne; j++) {   // r smallest tie indices
            int mi = j;
            for (int q = j + 1; q < ne; q++) if (ties[q] < ties[mi]) mi = q;
            int tmp = ties[mi]; ties[mi] = ties[j]; ties[j] = tmp;
            if (ng + j < TOPK) idxk[ng + j] = tmp;
        }
    }
    __syncthreads();
    if (tid < TOPK) wk[tid] = row[idxk[tid] & (NMEM - 1)];
    __syncthreads();
    if (tid == 0) {
        float m = wk[0];
        for (int i = 1; i < TOPK; i++) m = fmaxf(m, wk[i]);
        float ssum = 0.f;
        for (int i = 0; i < TOPK; i++) { float e = expf(wk[i] - m); wk[i] = e; ssum += e; }
        float inv = 1.0f / ssum;
        for (int i = 0; i < TOPK; i++) wk[i] *= inv;
    }
    __syncthreads();
    const float* mv = memv + (size_t)a * NMEM * DIM;
    float acc0 = 0.f, acc1 = 0.f;
    for (int i = 0; i < TOPK; i++) {
        const float* vr = mv + (size_t)(idxk[i] & (NMEM - 1)) * DIM;
        float w = wk[i];
        acc0 += w * vr[tid];
        acc1 += w * vr[tid + 256];
    }
    float* o = cur_next + (size_t)b * DIM;
    o[tid] = acc0;
    o[tid + 256] = acc1;
}

// ---------------------------------------------------------------------------
// 3-layer MLP (512->256 elu ->128 elu ->1). One block per row.
__global__ __launch_bounds__(256) void k_mlp(
    const float* __restrict__ x,
    const float* __restrict__ W1, const float* __restrict__ b1,
    const float* __restrict__ W2, const float* __restrict__ b2,
    const float* __restrict__ W3, const float* __restrict__ b3,
    float* __restrict__ out, int out_off, int out_stride) {
    int b = blockIdx.x, tid = threadIdx.x;
    __shared__ float xs[DIM];
    __shared__ float h1[H1N];
    __shared__ float h2[H2N];
    const float* xr = x + (size_t)b * DIM;
    xs[tid] = xr[tid];
    xs[tid + 256] = xr[tid + 256];
    __syncthreads();
    float acc = b1[tid];
    for (int k = 0; k < DIM; k++) acc += xs[k] * W1[k * H1N + tid];
    h1[tid] = (acc > 0.f) ? acc : expm1f(acc);
    __syncthreads();
    if (tid < H2N) {
        float a2 = b2[tid];
        for (int k = 0; k < H1N; k++) a2 += h1[k] * W2[k * H2N + tid];
        float h = (a2 > 0.f) ? a2 : expm1f(a2);
        h2[tid] = h * W3[tid];
    }
    __syncthreads();
    if (tid == 0) {
        float ssum = b3[0];
        for (int i = 0; i < H2N; i++) ssum += h2[i];
        out[out_off + b * out_stride] = ssum;
    }
}

// ---------------------------------------------------------------------------
extern "C" void kernel_launch(void* const* d_in, const int* in_sizes, int n_in,
                              void* d_out, int out_size, void* d_ws, size_t ws_size,
                              hipStream_t stream) {
    const float* emb  = (const float*)d_in[0];
    const float* keys = (const float*)d_in[1];
    const float* memv = (const float*)d_in[2];
    const float* W1 = (const float*)d_in[3];
    const float* b1 = (const float*)d_in[4];
    const float* W2 = (const float*)d_in[5];
    const float* b2 = (const float*)d_in[6];
    const float* W3 = (const float*)d_in[7];
    const float* b3 = (const float*)d_in[8];
    const int* actions = (const int*)d_in[9];
    float* out = (float*)d_out;

    char* ws = (char*)d_ws;
    size_t off = 0;
    auto alloc = [&](size_t bytes) -> void* {
        void* p = ws + off;
        off = (off + bytes + 255) & ~(size_t)255;
        return p;
    };
    float* inv_kn  = (float*)alloc(sizeof(float) * A_CNT * NMEM);
    float* qn      = (float*)alloc(sizeof(float) * NB * DIM);
    float* curA    = (float*)alloc(sizeof(float) * NB * DIM);
    float* curB    = (float*)alloc(sizeof(float) * NB * DIM);
    int* sorted_b  = (int*)alloc(sizeof(int) * NB);
    int* sorted_a  = (int*)alloc(sizeof(int) * NB);
    TileDesc* descs = (TileDesc*)alloc(sizeof(TileDesc) * 64);
    size_t rem = (ws_size > off) ? (ws_size - off) : 0;
    int CB = 256;
    if (rem >= sizeof(float) * (size_t)1024 * NMEM + 4096) CB = 1024;
    else if (rem >= sizeof(float) * (size_t)512 * NMEM + 4096) CB = 512;
    float* sims = (float*)alloc(sizeof(float) * (size_t)CB * NMEM);
    int nch = NB / CB;
    int maxd = CB / TM + A_CNT;

    k_inv_norm<<<dim3(A_CNT * NMEM / 4), dim3(256), 0, stream>>>(keys, inv_kn);
    k_mlp<<<dim3(NB), dim3(256), 0, stream>>>(emb, W1, b1, W2, b2, W3, b3, out, 0, 1);

    const float* cur = emb;
    float* nxt = curA;
    for (int t = 0; t < NSTEPS; t++) {
        k_group<<<dim3(1), dim3(64), 0, stream>>>(actions, t, sorted_b, sorted_a, descs, CB, maxd, nch);
        k_qnorm<<<dim3(NB), dim3(256), 0, stream>>>(cur, qn);
        for (int c = 0; c < nch; c++) {
            k_gemm<<<dim3(NMEM / TN, maxd), dim3(256), 0, stream>>>(
                qn, keys, inv_kn, sorted_b, descs + c * maxd, c * CB, sims);
            k_topk<<<dim3(CB), dim3(256), 0, stream>>>(
                sims, sorted_b, sorted_a, c * CB, memv, nxt);
        }
        k_mlp<<<dim3(NB), dim3(256), 0, stream>>>(nxt, W1, b1, W2, b2, W3, b3, out, NB + t, NSTEPS);
        cur = nxt;
        nxt = (nxt == curA) ? curB : curA;
    }
}

// Round 4
// 2347.565 us; speedup vs baseline: 1.1171x; 1.1171x over previous
//
#include <hip/hip_runtime.h>

#define A_CNT   5
#define NB      1024
#define DIM     512
#define NMEM    16384
#define TOPK    50
#define NSTEPS  5
#define H1N     256
#define H2N     128

#define TM      128
#define TN      128
#define KC      32
#define MSEL    100     // screen candidates per row (slack over TOPK=50)
#define RCAP    512     // candidate buffer cap (expected ~103)

struct TileDesc { int a; int s0; int nvalid; int pad; };

__device__ __forceinline__ unsigned fmap32(float f) {
    unsigned u = __float_as_uint(f);
    return (u & 0x80000000u) ? ~u : (u | 0x80000000u);
}

// ---------------------------------------------------------------------------
// ROUND-1 VERBATIM (selection-critical arithmetic — do not touch).
__global__ __launch_bounds__(256) void k_inv_norm(const float* __restrict__ keys,
                                                  float* __restrict__ inv) {
    int row  = blockIdx.x * 4 + (threadIdx.x >> 6);
    int lane = threadIdx.x & 63;
    const float* p = keys + (size_t)row * DIM;
    float ss = 0.f;
    for (int i = lane; i < DIM; i += 64) { float v = p[i]; ss += v * v; }
    for (int o = 32; o; o >>= 1) ss += __shfl_down(ss, o);
    ss = __shfl(ss, 0);
    if (lane == 0) inv[row] = 1.0f / (sqrtf(ss) + 1e-8f);
}

// ROUND-1 VERBATIM.
__global__ __launch_bounds__(256) void k_qnorm(const float* __restrict__ x,
                                               float* __restrict__ qn) {
    int row = blockIdx.x, tid = threadIdx.x;
    const float* p = x + (size_t)row * DIM;
    float ss = 0.f;
    for (int i = tid; i < DIM; i += 256) { float v = p[i]; ss += v * v; }
    for (int o = 32; o; o >>= 1) ss += __shfl_down(ss, o);
    __shared__ float w4[4];
    if ((tid & 63) == 0) w4[tid >> 6] = ss;
    __syncthreads();
    float tot = w4[0] + w4[1] + w4[2] + w4[3];
    float s = 1.0f / (sqrtf(tot) + 1e-8f);
    float* q = qn + (size_t)row * DIM;
    for (int i = tid; i < DIM; i += 256) q[i] = p[i] * s;
}

// ROUND-1 VERBATIM.
__global__ void k_group(const int* __restrict__ actions, int t,
                        int* __restrict__ sorted_b, int* __restrict__ sorted_a,
                        TileDesc* __restrict__ descs, int cb, int maxd, int nch) {
    int lane = threadIdx.x;  // blockDim = 64
    for (int i = lane; i < nch * maxd; i += 64) descs[i].a = -1;
    __shared__ int gs[A_CNT + 1];
    int out_pos = 0;
    for (int a = 0; a < A_CNT; a++) {
        if (lane == 0) gs[a] = out_pos;
        for (int c = 0; c < NB; c += 64) {
            int b = c + lane;
            int act = actions[b * NSTEPS + t];
            unsigned long long m = __ballot(act == a);
            int rank = __popcll(m & ((1ULL << lane) - 1ULL));
            if (act == a) { sorted_b[out_pos + rank] = b; sorted_a[out_pos + rank] = a; }
            out_pos += __popcll(m);
        }
    }
    if (lane == 0) {
        gs[A_CNT] = NB;
        int ndc[4] = {0, 0, 0, 0};
        for (int a = 0; a < A_CNT; a++) {
            int s = gs[a], e = gs[a + 1];
            while (s < e) {
                int c = s / cb;
                int lim = min(e, (c + 1) * cb);
                int len = min(TM, lim - s);
                TileDesc d; d.a = a; d.s0 = s; d.nvalid = len; d.pad = 0;
                descs[c * maxd + ndc[c]++] = d;
                s += len;
            }
        }
    }
}

// ---------------------------------------------------------------------------
// ROUND-1 VERBATIM f32 GEMM (bit-identical FMA chain: k ascending, 8x8 micro).
__global__ __launch_bounds__(256) void k_gemm(
    const float* __restrict__ qn, const float* __restrict__ keys,
    const float* __restrict__ inv_kn, const int* __restrict__ sorted_b,
    const TileDesc* __restrict__ descs, int chunk_row0,
    float* __restrict__ sims) {
    TileDesc d = descs[blockIdx.y];
    if (d.a < 0) return;
    int tid = threadIdx.x;
    int n0 = blockIdx.x * TN;
    __shared__ __align__(16) float As[KC][TM + 4];
    __shared__ __align__(16) float Bs[KC][TN + 4];
    __shared__ int rows[TM];
    if (tid < TM) {
        int s = d.s0 + min(tid, d.nvalid - 1);
        rows[tid] = sorted_b[s];
    }
    __syncthreads();
    float acc[8][8];
#pragma unroll
    for (int i = 0; i < 8; i++)
#pragma unroll
        for (int j = 0; j < 8; j++) acc[i][j] = 0.f;
    int ty = tid >> 4, tx = tid & 15;
    const float* kbase = keys + (size_t)d.a * NMEM * DIM;
    for (int k0 = 0; k0 < DIM; k0 += KC) {
#pragma unroll
        for (int i = 0; i < 4; i++) {       // A tile: 128 rows x 32 k
            int f4 = tid + i * 256;
            int r = f4 >> 3;
            int kq = (f4 & 7) * 4;
            float4 v = *(const float4*)(qn + (size_t)rows[r] * DIM + k0 + kq);
            As[kq + 0][r] = v.x; As[kq + 1][r] = v.y;
            As[kq + 2][r] = v.z; As[kq + 3][r] = v.w;
        }
#pragma unroll
        for (int i = 0; i < 4; i++) {       // B tile: 128 cols x 32 k
            int f4 = tid + i * 256;
            int n = f4 >> 3;
            int kq = (f4 & 7) * 4;
            float4 v = *(const float4*)(kbase + (size_t)(n0 + n) * DIM + k0 + kq);
            Bs[kq + 0][n] = v.x; Bs[kq + 1][n] = v.y;
            Bs[kq + 2][n] = v.z; Bs[kq + 3][n] = v.w;
        }
        __syncthreads();
#pragma unroll
        for (int k = 0; k < KC; k++) {
            float4 a0 = *(const float4*)&As[k][ty * 4];
            float4 a1 = *(const float4*)&As[k][64 + ty * 4];
            float4 b0 = *(const float4*)&Bs[k][tx * 4];
            float4 b1 = *(const float4*)&Bs[k][64 + tx * 4];
            float ar[8] = {a0.x, a0.y, a0.z, a0.w, a1.x, a1.y, a1.z, a1.w};
            float br[8] = {b0.x, b0.y, b0.z, b0.w, b1.x, b1.y, b1.z, b1.w};
#pragma unroll
            for (int i = 0; i < 8; i++)
#pragma unroll
                for (int j = 0; j < 8; j++) acc[i][j] += ar[i] * br[j];
        }
        __syncthreads();
    }
    // epilogue: scale by inv key norm, store
    const float* invp = inv_kn + (size_t)d.a * NMEM + n0;
    float invc[8];
#pragma unroll
    for (int j = 0; j < 4; j++) { invc[j] = invp[tx * 4 + j]; invc[4 + j] = invp[64 + tx * 4 + j]; }
    int sbase = d.s0 - chunk_row0;
#pragma unroll
    for (int i = 0; i < 8; i++) {
        int r = (i < 4) ? (ty * 4 + i) : (64 + ty * 4 + (i - 4));
        if (r < d.nvalid) {
            float* o = sims + (size_t)(sbase + r) * NMEM + n0;
            float4 s0, s1;
            s0.x = acc[i][0] * invc[0]; s0.y = acc[i][1] * invc[1];
            s0.z = acc[i][2] * invc[2]; s0.w = acc[i][3] * invc[3];
            s1.x = acc[i][4] * invc[4]; s1.y = acc[i][5] * invc[5];
            s1.z = acc[i][6] * invc[6]; s1.w = acc[i][7] * invc[7];
            *(float4*)(o + tx * 4) = s0;
            *(float4*)(o + 64 + tx * 4) = s1;
        }
    }
}

// ---------------------------------------------------------------------------
// NEW k_topk: register-cached row, deterministic 16-bit-key screen to >=100
// candidates, exact top-50 by (f32 desc, index asc) — identical selected set
// to round-1's exact radix select. Softmax + weighted gather.
__global__ __launch_bounds__(256) void k_topk(
    const float* __restrict__ sims,
    const int* __restrict__ sorted_b, const int* __restrict__ sorted_a,
    int chunk_row0,
    const float* __restrict__ memv, float* __restrict__ cur_next) {
    int tid = threadIdx.x;
    int s = chunk_row0 + blockIdx.x;
    int b = sorted_b[s], a = sorted_a[s];
    const float* row = sims + (size_t)blockIdx.x * NMEM;

    __shared__ unsigned hist[256];
    __shared__ unsigned sh_sel;
    __shared__ int sh_need;
    __shared__ unsigned cnum;
    __shared__ int   cidx[RCAP];
    __shared__ float cval[RCAP];
    __shared__ float selw[TOPK];
    __shared__ int   seli[TOPK];

    // cache full row in registers: 16 float4 per thread
    float f[64];
#pragma unroll
    for (int c = 0; c < 16; c++) {
        float4 v = *(const float4*)(row + (size_t)(c * 256 + tid) * 4);
        f[c * 4 + 0] = v.x; f[c * 4 + 1] = v.y; f[c * 4 + 2] = v.z; f[c * 4 + 3] = v.w;
    }

    // radix screen, pass 0: top byte of ordered-uint map
    hist[tid] = 0;
    if (tid == 0) cnum = 0;
    __syncthreads();
#pragma unroll
    for (int i = 0; i < 64; i++) atomicAdd(&hist[fmap32(f[i]) >> 24], 1u);
    __syncthreads();
    if (tid == 0) {
        int need = MSEL; unsigned bsel = 0;
        for (int bb = 255; bb >= 0; bb--) {
            int c = (int)hist[bb];
            if (c >= need) { bsel = (unsigned)bb; break; }
            need -= c;
        }
        sh_sel = bsel; sh_need = need;
    }
    __syncthreads();
    unsigned b0 = sh_sel;
    hist[tid] = 0;
    __syncthreads();
    // pass 1: second byte among top-byte == b0
#pragma unroll
    for (int i = 0; i < 64; i++) {
        unsigned k16 = fmap32(f[i]) >> 16;
        if ((k16 >> 8) == b0) atomicAdd(&hist[k16 & 255], 1u);
    }
    __syncthreads();
    if (tid == 0) {
        int need = sh_need; unsigned lsel = 0;
        for (int bb = 255; bb >= 0; bb--) {
            int c = (int)hist[bb];
            if (c >= need) { lsel = (unsigned)bb; break; }
            need -= c;
        }
        sh_sel = (b0 << 8) | lsel;
    }
    __syncthreads();
    unsigned tau16 = sh_sel;

    // collect candidates: key16 >= tau16 (>= MSEL of them; every true top-50
    // member included: excluded => key16 < tau16 => strictly smaller f32 than
    // >=100 candidates).
#pragma unroll
    for (int c = 0; c < 16; c++)
#pragma unroll
        for (int e = 0; e < 4; e++) {
            float x = f[c * 4 + e];
            if ((fmap32(x) >> 16) >= tau16) {
                unsigned p = atomicAdd(&cnum, 1u);
                if (p < RCAP) { cidx[p] = (c * 256 + tid) * 4 + e; cval[p] = x; }
            }
        }
    __syncthreads();
    int ncand = (int)cnum; if (ncand > RCAP) ncand = RCAP;

    // exact rank select among candidates (f32 desc, index asc)
    for (int i = tid; i < ncand; i += 256) {
        float si = cval[i]; int ni = cidx[i];
        int rank = 0;
        for (int j = 0; j < ncand; j++) {
            float sj = cval[j];
            rank += (sj > si) || (sj == si && cidx[j] < ni);
        }
        if (rank < TOPK) { selw[rank] = si; seli[rank] = ni; }
    }
    __syncthreads();
    if (tid == 0) {
        float mx = selw[0];
        for (int i = 1; i < TOPK; i++) mx = fmaxf(mx, selw[i]);
        float ssum = 0.f;
        for (int i = 0; i < TOPK; i++) { float e = expf(selw[i] - mx); selw[i] = e; ssum += e; }
        float inv = 1.0f / ssum;
        for (int i = 0; i < TOPK; i++) selw[i] *= inv;
    }
    __syncthreads();

    const float* mv = memv + (size_t)a * NMEM * DIM;
    float acc0 = 0.f, acc1 = 0.f;
#pragma unroll 10
    for (int i = 0; i < TOPK; i++) {
        const float* vr = mv + (size_t)seli[i] * DIM;
        float wgt = selw[i];
        acc0 += wgt * vr[tid];
        acc1 += wgt * vr[tid + 256];
    }
    float* o = cur_next + (size_t)b * DIM;
    o[tid] = acc0;
    o[tid + 256] = acc1;
}

// ---------------------------------------------------------------------------
// NEW k_mlp: 4 rows/block, one wave per row. Layer1: 4 cols/lane; layer2:
// 2 cols/lane; layer3: shuffle reduce. Continuous reordering vs reference.
__global__ __launch_bounds__(256) void k_mlp(
    const float* __restrict__ x,
    const float* __restrict__ W1, const float* __restrict__ b1,
    const float* __restrict__ W2, const float* __restrict__ b2,
    const float* __restrict__ W3, const float* __restrict__ b3,
    float* __restrict__ out, int out_off, int out_stride) {
    int w = threadIdx.x >> 6, lane = threadIdx.x & 63;
    int b = blockIdx.x * 4 + w;
    __shared__ float xs[4][DIM];
    __shared__ float h1s[4][H1N];
    const float* xr = x + (size_t)b * DIM;
#pragma unroll
    for (int i = 0; i < 2; i++) {
        float4 v = *(const float4*)(xr + (lane + i * 64) * 4);
        *(float4*)&xs[w][(lane + i * 64) * 4] = v;
    }
    __syncthreads();
    float a0 = b1[lane], a1 = b1[lane + 64], a2 = b1[lane + 128], a3 = b1[lane + 192];
    for (int k = 0; k < DIM; k++) {
        float xv = xs[w][k];
        const float* wr = W1 + k * H1N;
        a0 += xv * wr[lane];
        a1 += xv * wr[lane + 64];
        a2 += xv * wr[lane + 128];
        a3 += xv * wr[lane + 192];
    }
    h1s[w][lane]       = (a0 > 0.f) ? a0 : expm1f(a0);
    h1s[w][lane + 64]  = (a1 > 0.f) ? a1 : expm1f(a1);
    h1s[w][lane + 128] = (a2 > 0.f) ? a2 : expm1f(a2);
    h1s[w][lane + 192] = (a3 > 0.f) ? a3 : expm1f(a3);
    __syncthreads();
    float c0 = b2[lane], c1 = b2[lane + 64];
    for (int k = 0; k < H1N; k++) {
        float hv = h1s[w][k];
        c0 += hv * W2[k * H2N + lane];
        c1 += hv * W2[k * H2N + lane + 64];
    }
    c0 = ((c0 > 0.f) ? c0 : expm1f(c0)) * W3[lane];
    c1 = ((c1 > 0.f) ? c1 : expm1f(c1)) * W3[lane + 64];
    float ssum = c0 + c1;
    for (int o = 32; o; o >>= 1) ssum += __shfl_down(ssum, o);
    if (lane == 0) out[out_off + b * out_stride] = ssum + b3[0];
}

// ---------------------------------------------------------------------------
extern "C" void kernel_launch(void* const* d_in, const int* in_sizes, int n_in,
                              void* d_out, int out_size, void* d_ws, size_t ws_size,
                              hipStream_t stream) {
    const float* emb  = (const float*)d_in[0];
    const float* keys = (const float*)d_in[1];
    const float* memv = (const float*)d_in[2];
    const float* W1 = (const float*)d_in[3];
    const float* b1 = (const float*)d_in[4];
    const float* W2 = (const float*)d_in[5];
    const float* b2 = (const float*)d_in[6];
    const float* W3 = (const float*)d_in[7];
    const float* b3 = (const float*)d_in[8];
    const int* actions = (const int*)d_in[9];
    float* out = (float*)d_out;

    char* ws = (char*)d_ws;
    size_t off = 0;
    auto alloc = [&](size_t bytes) -> void* {
        void* p = ws + off;
        off = (off + bytes + 255) & ~(size_t)255;
        return p;
    };
    float* inv_kn  = (float*)alloc(sizeof(float) * A_CNT * NMEM);
    float* qn      = (float*)alloc(sizeof(float) * NB * DIM);
    float* curA    = (float*)alloc(sizeof(float) * NB * DIM);
    float* curB    = (float*)alloc(sizeof(float) * NB * DIM);
    int* sorted_b  = (int*)alloc(sizeof(int) * NB);
    int* sorted_a  = (int*)alloc(sizeof(int) * NB);
    TileDesc* descs = (TileDesc*)alloc(sizeof(TileDesc) * 64);
    size_t rem = (ws_size > off) ? (ws_size - off) : 0;
    int CB = 256;
    if (rem >= sizeof(float) * (size_t)1024 * NMEM + 4096) CB = 1024;
    else if (rem >= sizeof(float) * (size_t)512 * NMEM + 4096) CB = 512;
    float* sims = (float*)alloc(sizeof(float) * (size_t)CB * NMEM);
    int nch = NB / CB;
    int maxd = CB / TM + A_CNT;

    k_inv_norm<<<dim3(A_CNT * NMEM / 4), dim3(256), 0, stream>>>(keys, inv_kn);
    k_mlp<<<dim3(NB / 4), dim3(256), 0, stream>>>(emb, W1, b1, W2, b2, W3, b3, out, 0, 1);

    const float* cur = emb;
    float* nxt = curA;
    for (int t = 0; t < NSTEPS; t++) {
        k_group<<<dim3(1), dim3(64), 0, stream>>>(actions, t, sorted_b, sorted_a, descs, CB, maxd, nch);
        k_qnorm<<<dim3(NB), dim3(256), 0, stream>>>(cur, qn);
        for (int c = 0; c < nch; c++) {
            k_gemm<<<dim3(NMEM / TN, maxd), dim3(256), 0, stream>>>(
                qn, keys, inv_kn, sorted_b, descs + c * maxd, c * CB, sims);
            k_topk<<<dim3(CB), dim3(256), 0, stream>>>(
                sims, sorted_b, sorted_a, c * CB, memv, nxt);
        }
        k_mlp<<<dim3(NB / 4), dim3(256), 0, stream>>>(nxt, W1, b1, W2, b2, W3, b3, out, NB + t, NSTEPS);
        cur = nxt;
        nxt = (nxt == curA) ? curB : curA;
    }
}